// Round 2
// baseline (646.022 us; speedup 1.0000x reference)
//
#include <hip/hip_runtime.h>
#include <float.h>

#define K_CODES 1024
#define D_DIM   256
#define PT      64    // points per block
#define CT      256   // codes per tile
#define DC      32    // dims per LDS chunk

// ---- numpy-pairwise fp32 sum-of-squares over 256 elements ----------------
// numpy pairwise_sum(n=256): split 128+128; each 128-block: 8 accumulators
// r[j] = x[j] + x[8+j] + ... + x[120+j] (sequential), combined as
// ((r0+r1)+(r2+r3)) + ((r4+r5)+(r6+r7)); total = S(0:128) + S(128:256).
// fp contract OFF: numpy rounds z*z separately from the additions.

// znorm[n] = ||z_flat[n]||^2, n = b*1024 + h*32 + w; z is [B][D][H][W] so
// element d of point n sits at z[b*D*1024 + d*1024 + hw] (stride 1024).
__global__ __launch_bounds__(256) void znorm_kernel(const float* __restrict__ z,
                                                    float* __restrict__ znorm) {
#pragma clang fp contract(off) reassociate(off)
    const int n = blockIdx.x * 256 + threadIdx.x;
    const int b = n >> 10, hw = n & 1023;
    const float* zp = z + (size_t)b * (D_DIM * 1024) + hw;
    float tot0, tot1;
    {
        float r[8];
#pragma unroll
        for (int j = 0; j < 8; ++j) { float x = zp[(size_t)j * 1024]; r[j] = x * x; }
        for (int i = 1; i < 16; ++i) {
#pragma unroll
            for (int j = 0; j < 8; ++j) {
                float x = zp[(size_t)(8 * i + j) * 1024];
                r[j] = r[j] + x * x;
            }
        }
        tot0 = ((r[0] + r[1]) + (r[2] + r[3])) + ((r[4] + r[5]) + (r[6] + r[7]));
    }
    {
        const float* zq = zp + (size_t)128 * 1024;
        float r[8];
#pragma unroll
        for (int j = 0; j < 8; ++j) { float x = zq[(size_t)j * 1024]; r[j] = x * x; }
        for (int i = 1; i < 16; ++i) {
#pragma unroll
            for (int j = 0; j < 8; ++j) {
                float x = zq[(size_t)(8 * i + j) * 1024];
                r[j] = r[j] + x * x;
            }
        }
        tot1 = ((r[0] + r[1]) + (r[2] + r[3])) + ((r[4] + r[5]) + (r[6] + r[7]));
    }
    znorm[n] = tot0 + tot1;
}

// enorm[c] = ||emb[c]||^2 with the same numpy-pairwise order (contiguous row).
__global__ __launch_bounds__(256) void enorm_kernel(const float* __restrict__ emb,
                                                    float* __restrict__ enorm) {
#pragma clang fp contract(off) reassociate(off)
    const int c = blockIdx.x * 256 + threadIdx.x;
    const float* e = emb + (size_t)c * D_DIM;
    float tot0, tot1;
    {
        float r[8];
#pragma unroll
        for (int j = 0; j < 8; ++j) { float x = e[j]; r[j] = x * x; }
        for (int i = 1; i < 16; ++i) {
#pragma unroll
            for (int j = 0; j < 8; ++j) { float x = e[8 * i + j]; r[j] = r[j] + x * x; }
        }
        tot0 = ((r[0] + r[1]) + (r[2] + r[3])) + ((r[4] + r[5]) + (r[6] + r[7]));
    }
    {
        const float* e2 = e + 128;
        float r[8];
#pragma unroll
        for (int j = 0; j < 8; ++j) { float x = e2[j]; r[j] = x * x; }
        for (int i = 1; i < 16; ++i) {
#pragma unroll
            for (int j = 0; j < 8; ++j) { float x = e2[8 * i + j]; r[j] = r[j] + x * x; }
        }
        tot1 = ((r[0] + r[1]) + (r[2] + r[3])) + ((r[4] + r[5]) + (r[6] + r[7]));
    }
    enorm[c] = tot0 + tot1;
}

// Main: per block, 64 points vs all 1024 codes, fused argmin.
// Score replicates reference fp32 semantics: fl(fl(znorm - 2*dot) + enorm).
__global__ __launch_bounds__(256) void vq_kernel(const float* __restrict__ z,
                                                 const float* __restrict__ emb,
                                                 const float* __restrict__ enorm,
                                                 const float* __restrict__ znorm,
                                                 int* __restrict__ out) {
    __shared__ float zc[DC * PT];        // [d][p]  8 KB
    __shared__ float ec[DC * CT];        // [d][c] 32 KB
    __shared__ float redv[PT * 17];
    __shared__ int   redi[PT * 17];

    const int t  = threadIdx.x;
    const int pg = t >> 4;
    const int cg = t & 15;
    const int pb = blockIdx.x;                  // 0..1023
    const int b  = pb >> 4;
    const int hw0 = (pb & 15) << 6;
    const float* zbase = z + (size_t)b * (D_DIM * 1024) + hw0;  // +d*1024+p

    float zn[4];
#pragma unroll
    for (int i = 0; i < 4; ++i) zn[i] = znorm[pb * PT + 4 * pg + i];

    float best_v[4];
    int   best_i[4];
#pragma unroll
    for (int i = 0; i < 4; ++i) { best_v[i] = FLT_MAX; best_i[i] = 0; }

    for (int tile = 0; tile < K_CODES / CT; ++tile) {
        float acc[4][16];
#pragma unroll
        for (int i = 0; i < 4; ++i)
#pragma unroll
            for (int j = 0; j < 16; ++j) acc[i][j] = 0.f;

        for (int chunk = 0; chunk < D_DIM / DC; ++chunk) {
            const int d0 = chunk * DC;
            __syncthreads();
            {   // stage z chunk: coalesced
                int p = t & 63, dp = t >> 6;
#pragma unroll
                for (int r = 0; r < 8; ++r) {
                    int d = 4 * r + dp;
                    zc[d * PT + p] = zbase[(size_t)(d0 + d) * 1024 + p];
                }
            }
            {   // stage e chunk (transposed to [d][c])
                int q = t & 7, cr = t >> 3;
#pragma unroll
                for (int r = 0; r < 8; ++r) {
                    int cl = 32 * r + cr;
                    int c  = tile * CT + cl;
                    float4 v = *(const float4*)(emb + (size_t)c * D_DIM + d0 + 4 * q);
                    int dd = 4 * q;
                    ec[(dd + 0) * CT + cl] = v.x;
                    ec[(dd + 1) * CT + cl] = v.y;
                    ec[(dd + 2) * CT + cl] = v.z;
                    ec[(dd + 3) * CT + cl] = v.w;
                }
            }
            __syncthreads();
#pragma unroll 4
            for (int d = 0; d < DC; ++d) {
                float4 zf = *(const float4*)&zc[d * PT + 4 * pg];
                float4 ef[4];
#pragma unroll
                for (int j = 0; j < 4; ++j)
                    ef[j] = *(const float4*)&ec[d * CT + 64 * j + 4 * cg];
                const float zz[4] = { zf.x, zf.y, zf.z, zf.w };
#pragma unroll
                for (int i = 0; i < 4; ++i) {
                    float zi = zz[i];
#pragma unroll
                    for (int j = 0; j < 4; ++j) {
                        acc[i][4 * j + 0] += zi * ef[j].x;
                        acc[i][4 * j + 1] += zi * ef[j].y;
                        acc[i][4 * j + 2] += zi * ef[j].z;
                        acc[i][4 * j + 3] += zi * ef[j].w;
                    }
                }
            }
        }
        // epilogue: sc = fl(fl(zn - 2*acc) + enorm); codes ascending in-thread
        {
#pragma clang fp contract(off) reassociate(off)
#pragma unroll
            for (int j = 0; j < 4; ++j) {
#pragma unroll
                for (int jj = 0; jj < 4; ++jj) {
                    int c = tile * CT + 64 * j + 4 * cg + jj;
                    float en = enorm[c];
#pragma unroll
                    for (int i = 0; i < 4; ++i) {
                        float t1 = zn[i] - 2.0f * acc[i][4 * j + jj];
                        float sc = t1 + en;
                        if (sc < best_v[i] || (sc == best_v[i] && c < best_i[i])) {
                            best_v[i] = sc; best_i[i] = c;
                        }
                    }
                }
            }
        }
    }

#pragma unroll
    for (int i = 0; i < 4; ++i) {
        int p = 4 * pg + i;
        redv[p * 17 + cg] = best_v[i];
        redi[p * 17 + cg] = best_i[i];
    }
    __syncthreads();
    if (t < PT) {
        float bv = FLT_MAX; int bi = 0;
        for (int g = 0; g < 16; ++g) {
            float v = redv[t * 17 + g];
            int  ix = redi[t * 17 + g];
            if (v < bv || (v == bv && ix < bi)) { bv = v; bi = ix; }
        }
        out[pb * PT + t] = bi;
    }
}

extern "C" void kernel_launch(void* const* d_in, const int* in_sizes, int n_in,
                              void* d_out, int out_size, void* d_ws, size_t ws_size,
                              hipStream_t stream) {
    const float* z   = (const float*)d_in[0];   // [64,256,32,32]
    const float* emb = (const float*)d_in[1];   // [1024,256]
    float* enorm = (float*)d_ws;                // 1024 floats
    float* znorm = (float*)d_ws + K_CODES;      // 65536 floats
    int*   out   = (int*)d_out;                 // [64,32,32] int32

    enorm_kernel<<<K_CODES / 256, 256, 0, stream>>>(emb, enorm);
    znorm_kernel<<<65536 / 256, 256, 0, stream>>>(z, znorm);
    vq_kernel<<<65536 / PT, 256, 0, stream>>>(z, emb, enorm, znorm, out);
}

// Round 3
// 387.708 us; speedup vs baseline: 1.6663x; 1.6663x over previous
//
#include <hip/hip_runtime.h>
#include <float.h>
#include <stdint.h>

#define K_CODES 1024
#define D_DIM   256
#define NPTS    65536
#define K2      512           // [zh | zl] interleaved K
#define CAP     32
#define DELTA   2e-3f

using short8  = __attribute__((ext_vector_type(8))) short;
using float4v = __attribute__((ext_vector_type(4))) float;

// ---------------- workspace layout (bytes) ----------------
#define A2_OFF     ((size_t)0)
#define A2_BYTES   ((size_t)NPTS * K2 * 2)          // 64 MB  bf16 [n][512]
#define B2_OFF     (A2_OFF + A2_BYTES)
#define B2_BYTES   ((size_t)K_CODES * K2 * 2)       // 1 MB   bf16 [c][512]
#define EN_OFF     (B2_OFF + B2_BYTES)
#define EN_BYTES   ((size_t)K_CODES * 4)
#define ZN_OFF     (EN_OFF + EN_BYTES)
#define ZN_BYTES   ((size_t)NPTS * 4)
#define CNT_OFF    (ZN_OFF + ZN_BYTES)
#define CNT_BYTES  ((size_t)NPTS * 4)
#define CAND_OFF   (CNT_OFF + CNT_BYTES)
#define CAND_BYTES ((size_t)NPTS * CAP * 4)
#define WS_NEED    (CAND_OFF + CAND_BYTES)          // ~77.1 MB

// fallback (R2 path) scratch
#define FB_EN_OFF 0
#define FB_ZN_OFF ((size_t)K_CODES * 4)

__device__ __forceinline__ uint16_t f2bf(float x) {   // RNE fp32->bf16
    uint32_t u = __float_as_uint(x);
    return (uint16_t)((u + 0x7FFFu + ((u >> 16) & 1u)) >> 16);
}
__device__ __forceinline__ float bf2f(uint16_t h) {
    return __uint_as_float(((uint32_t)h) << 16);
}
__device__ __forceinline__ unsigned enc_f(float f) {  // order-preserving
    unsigned u = __float_as_uint(f);
    return (u & 0x80000000u) ? ~u : (u | 0x80000000u);
}
__device__ __forceinline__ float dec_f(unsigned u) {
    unsigned v = (u & 0x80000000u) ? (u & 0x7FFFFFFFu) : ~u;
    return __uint_as_float(v);
}
__device__ __forceinline__ void gl_lds16(const void* g, void* l) {
    __builtin_amdgcn_global_load_lds(
        (const __attribute__((address_space(1))) void*)g,
        (__attribute__((address_space(3))) void*)l, 16, 0, 0);
}

// ---------------- exact norms (numpy-pairwise fp32, contract off) ---------
__global__ __launch_bounds__(256) void znorm_kernel(const float* __restrict__ z,
                                                    float* __restrict__ znorm) {
#pragma clang fp contract(off) reassociate(off)
    const int n = blockIdx.x * 256 + threadIdx.x;
    const int b = n >> 10, hw = n & 1023;
    const float* zp = z + (size_t)b * (D_DIM * 1024) + hw;
    float tot0, tot1;
    {
        float r[8];
#pragma unroll
        for (int j = 0; j < 8; ++j) { float x = zp[(size_t)j * 1024]; r[j] = x * x; }
        for (int i = 1; i < 16; ++i) {
#pragma unroll
            for (int j = 0; j < 8; ++j) {
                float x = zp[(size_t)(8 * i + j) * 1024];
                r[j] = r[j] + x * x;
            }
        }
        tot0 = ((r[0] + r[1]) + (r[2] + r[3])) + ((r[4] + r[5]) + (r[6] + r[7]));
    }
    {
        const float* zq = zp + (size_t)128 * 1024;
        float r[8];
#pragma unroll
        for (int j = 0; j < 8; ++j) { float x = zq[(size_t)j * 1024]; r[j] = x * x; }
        for (int i = 1; i < 16; ++i) {
#pragma unroll
            for (int j = 0; j < 8; ++j) {
                float x = zq[(size_t)(8 * i + j) * 1024];
                r[j] = r[j] + x * x;
            }
        }
        tot1 = ((r[0] + r[1]) + (r[2] + r[3])) + ((r[4] + r[5]) + (r[6] + r[7]));
    }
    znorm[n] = tot0 + tot1;
}

__global__ __launch_bounds__(256) void enorm_kernel(const float* __restrict__ emb,
                                                    float* __restrict__ enorm) {
#pragma clang fp contract(off) reassociate(off)
    const int c = blockIdx.x * 256 + threadIdx.x;
    const float* e = emb + (size_t)c * D_DIM;
    float tot0, tot1;
    {
        float r[8];
#pragma unroll
        for (int j = 0; j < 8; ++j) { float x = e[j]; r[j] = x * x; }
        for (int i = 1; i < 16; ++i) {
#pragma unroll
            for (int j = 0; j < 8; ++j) { float x = e[8 * i + j]; r[j] = r[j] + x * x; }
        }
        tot0 = ((r[0] + r[1]) + (r[2] + r[3])) + ((r[4] + r[5]) + (r[6] + r[7]));
    }
    {
        const float* e2 = e + 128;
        float r[8];
#pragma unroll
        for (int j = 0; j < 8; ++j) { float x = e2[j]; r[j] = x * x; }
        for (int i = 1; i < 16; ++i) {
#pragma unroll
            for (int j = 0; j < 8; ++j) { float x = e2[8 * i + j]; r[j] = r[j] + x * x; }
        }
        tot1 = ((r[0] + r[1]) + (r[2] + r[3])) + ((r[4] + r[5]) + (r[6] + r[7]));
    }
    enorm[c] = tot0 + tot1;
}

// ---------------- bf16 split conversions ----------------
// B2[c][k]: k<256 -> bf16(e), k>=256 -> bf16(e - hi)
__global__ __launch_bounds__(256) void conv_e_kernel(const float* __restrict__ emb,
                                                     uint16_t* __restrict__ B2) {
    const int c = blockIdx.x, d = threadIdx.x;
    float x = emb[(size_t)c * D_DIM + d];
    uint16_t h = f2bf(x);
    uint16_t l = f2bf(x - bf2f(h));
    B2[(size_t)c * K2 + d]         = h;
    B2[(size_t)c * K2 + 256 + d]   = l;
}

// A2[n][k] from z[b][d][hw]: block = 64 points, LDS transpose per 64-d tile.
__global__ __launch_bounds__(256) void conv_z_kernel(const float* __restrict__ z,
                                                     uint16_t* __restrict__ A2) {
    __shared__ float ld[64 * 65];
    const int t = threadIdx.x;
    const int pb = blockIdx.x;                 // 0..1023
    const int b = pb >> 4, hw0 = (pb & 15) << 6;
    const float* zb = z + (size_t)b * (D_DIM * 1024) + hw0;
    const int w = t >> 6, p = t & 63;          // read mapping
    const int p2 = t >> 2, qq = t & 3;         // write mapping

    for (int dt = 0; dt < 4; ++dt) {
        __syncthreads();
#pragma unroll
        for (int r = 0; r < 16; ++r) {
            int dl = w + 4 * r;
            ld[dl * 65 + p] = zb[(size_t)(dt * 64 + dl) * 1024 + p];
        }
        __syncthreads();
        uint16_t hs[16], ls[16];
#pragma unroll
        for (int i = 0; i < 16; ++i) {
            float v = ld[(qq * 16 + i) * 65 + p2];
            uint16_t h = f2bf(v);
            hs[i] = h;
            ls[i] = f2bf(v - bf2f(h));
        }
        size_t nbase = (size_t)(pb * 64 + p2) * K2 + dt * 64 + qq * 16;
#pragma unroll
        for (int g = 0; g < 4; ++g) {
            *(ushort4*)&A2[nbase + 4 * g] =
                make_ushort4(hs[4 * g], hs[4 * g + 1], hs[4 * g + 2], hs[4 * g + 3]);
            *(ushort4*)&A2[nbase + 256 + 4 * g] =
                make_ushort4(ls[4 * g], ls[4 * g + 1], ls[4 * g + 2], ls[4 * g + 3]);
        }
    }
}

// ---------------- phase 1: bf16x2-split MFMA GEMM + candidate filter ------
// block = 64 points x 256-code tiles (x4), wave tile 64x64, mfma 16x16x32.
__global__ __launch_bounds__(256) void vq_mfma_kernel(const uint16_t* __restrict__ A2,
                                                      const uint16_t* __restrict__ B2,
                                                      const float* __restrict__ enorm,
                                                      unsigned* __restrict__ cnt,
                                                      unsigned* __restrict__ cand) {
    __shared__ short As[64 * 64];     //  8 KB [row(m)][k]
    __shared__ short Bs[256 * 64];    // 32 KB [row(c)][k]
    __shared__ unsigned pmin[64];

    const int t    = threadIdx.x;
    const int w    = t >> 6;          // wave 0..3
    const int ln   = t & 63;
    const int quad = ln >> 4;
    const int col  = ln & 15;
    const int l3   = ln >> 3, l7 = ln & 7;
    const int pb   = blockIdx.x;      // 0..1023

    if (t < 64) pmin[t] = 0xFFFFFFFFu;

    const int arow = pb * 64 + w * 16 + l3;     // + i*8

    for (int ct = 0; ct < 4; ++ct) {
        float4v s[4][4];
#pragma unroll
        for (int i = 0; i < 4; ++i)
#pragma unroll
            for (int j = 0; j < 4; ++j) s[i][j] = (float4v)0.0f;

        for (int chunk = 0; chunk < 8; ++chunk) {
            const int k0 = chunk * 64;
            __syncthreads();
            // stage A: 2 issues/lane (8 rows/issue/wave)
#pragma unroll
            for (int i = 0; i < 2; ++i) {
                gl_lds16(A2 + (size_t)(arow + i * 8) * K2 + k0 + l7 * 8,
                         &As[w * 1024 + i * 512]);
            }
            // stage B: 8 issues/lane
#pragma unroll
            for (int i = 0; i < 8; ++i) {
                int c = ct * 256 + w * 64 + i * 8 + l3;
                gl_lds16(B2 + (size_t)c * K2 + k0 + l7 * 8,
                         &Bs[w * 4096 + i * 512]);
            }
            __syncthreads();
#pragma unroll
            for (int kh = 0; kh < 2; ++kh) {
                const int kk = kh * 32 + quad * 8;
                short8 a[4], bfr[4];
#pragma unroll
                for (int tm = 0; tm < 4; ++tm)
                    a[tm] = *(const short8*)&As[(tm * 16 + col) * 64 + kk];
#pragma unroll
                for (int tn = 0; tn < 4; ++tn)
                    bfr[tn] = *(const short8*)&Bs[(w * 64 + tn * 16 + col) * 64 + kk];
#pragma unroll
                for (int tm = 0; tm < 4; ++tm)
#pragma unroll
                    for (int tn = 0; tn < 4; ++tn)
                        s[tm][tn] = __builtin_amdgcn_mfma_f32_16x16x32_bf16(
                            a[tm], bfr[tn], s[tm][tn], 0, 0, 0);
            }
        }
        // epilogue: sc = enorm - 2*dot ; running block min + candidate push
        float en4[4];
#pragma unroll
        for (int tn = 0; tn < 4; ++tn)
            en4[tn] = enorm[ct * 256 + w * 64 + tn * 16 + col];
#pragma unroll
        for (int tm = 0; tm < 4; ++tm)
#pragma unroll
            for (int tn = 0; tn < 4; ++tn)
#pragma unroll
                for (int r = 0; r < 4; ++r)
                    s[tm][tn][r] = en4[tn] - 2.0f * s[tm][tn][r];
#pragma unroll
        for (int tm = 0; tm < 4; ++tm)
#pragma unroll
            for (int r = 0; r < 4; ++r) {
                float v = fminf(fminf(s[tm][0][r], s[tm][1][r]),
                                fminf(s[tm][2][r], s[tm][3][r]));
                atomicMin(&pmin[tm * 16 + quad * 4 + r], enc_f(v));
            }
        __syncthreads();
#pragma unroll
        for (int tm = 0; tm < 4; ++tm)
#pragma unroll
            for (int r = 0; r < 4; ++r) {
                const int m = tm * 16 + quad * 4 + r;
                const float thr = dec_f(pmin[m]) + DELTA;
                const unsigned n = pb * 64 + m;
#pragma unroll
                for (int tn = 0; tn < 4; ++tn) {
                    if (s[tm][tn][r] <= thr) {
                        unsigned c = ct * 256 + w * 64 + tn * 16 + col;
                        unsigned idx = atomicAdd(&cnt[n], 1u);
                        if (idx < CAP) cand[(size_t)n * CAP + idx] = c;
                    }
                }
            }
    }
}

// ---------------- phase 2: exact fp32 rescore of candidates ---------------
__global__ __launch_bounds__(256) void rescore_kernel(const float* __restrict__ z,
                                                      const float* __restrict__ emb,
                                                      const float* __restrict__ enorm,
                                                      const float* __restrict__ znorm,
                                                      const unsigned* __restrict__ cnt,
                                                      const unsigned* __restrict__ cand,
                                                      int* __restrict__ out) {
    const int n = blockIdx.x * 256 + threadIdx.x;
    const int b = n >> 10, hw = n & 1023;
    const float* zp = z + (size_t)b * (D_DIM * 1024) + hw;
    int k = (int)cnt[n];
    if (k > CAP) k = CAP;
    if (k < 1) k = 1;                     // can't happen; deterministic guard
    const float zn = znorm[n];
    float bv = FLT_MAX;
    int   bi = 0x7FFFFFFF;
    for (int g0 = 0; g0 < k; g0 += 4) {
        int gk = k - g0; if (gk > 4) gk = 4;
        int cs[4];
        float dot[4];
#pragma unroll
        for (int j = 0; j < 4; ++j) { dot[j] = 0.f; cs[j] = 0; }
        for (int j = 0; j < gk; ++j) cs[j] = (int)cand[(size_t)n * CAP + g0 + j];
        for (int d = 0; d < D_DIM; ++d) {
            float zv = zp[(size_t)d * 1024];
#pragma unroll
            for (int j = 0; j < 4; ++j)
                dot[j] = __builtin_fmaf(zv, emb[(size_t)cs[j] * D_DIM + d], dot[j]);
        }
        {
#pragma clang fp contract(off) reassociate(off)
            for (int j = 0; j < gk; ++j) {
                float t1 = zn - 2.0f * dot[j];
                float sc = t1 + enorm[cs[j]];
                if (sc < bv || (sc == bv && cs[j] < bi)) { bv = sc; bi = cs[j]; }
            }
        }
    }
    out[n] = bi;
}

// ================= R2 fallback (exact fp32 VALU path) =====================
#define PT 64
#define CT 256
#define DC 32
__global__ __launch_bounds__(256) void vq_kernel(const float* __restrict__ z,
                                                 const float* __restrict__ emb,
                                                 const float* __restrict__ enorm,
                                                 const float* __restrict__ znorm,
                                                 int* __restrict__ out) {
    __shared__ float zc[DC * PT];
    __shared__ float ec[DC * CT];
    __shared__ float redv[PT * 17];
    __shared__ int   redi[PT * 17];
    const int t  = threadIdx.x;
    const int pg = t >> 4;
    const int cg = t & 15;
    const int pb = blockIdx.x;
    const int b  = pb >> 4;
    const int hw0 = (pb & 15) << 6;
    const float* zbase = z + (size_t)b * (D_DIM * 1024) + hw0;
    float zn[4];
#pragma unroll
    for (int i = 0; i < 4; ++i) zn[i] = znorm[pb * PT + 4 * pg + i];
    float best_v[4]; int best_i[4];
#pragma unroll
    for (int i = 0; i < 4; ++i) { best_v[i] = FLT_MAX; best_i[i] = 0; }
    for (int tile = 0; tile < K_CODES / CT; ++tile) {
        float acc[4][16];
#pragma unroll
        for (int i = 0; i < 4; ++i)
#pragma unroll
            for (int j = 0; j < 16; ++j) acc[i][j] = 0.f;
        for (int chunk = 0; chunk < D_DIM / DC; ++chunk) {
            const int d0 = chunk * DC;
            __syncthreads();
            {
                int p = t & 63, dp = t >> 6;
#pragma unroll
                for (int r = 0; r < 8; ++r) {
                    int d = 4 * r + dp;
                    zc[d * PT + p] = zbase[(size_t)(d0 + d) * 1024 + p];
                }
            }
            {
                int q = t & 7, cr = t >> 3;
#pragma unroll
                for (int r = 0; r < 8; ++r) {
                    int cl = 32 * r + cr;
                    int c  = tile * CT + cl;
                    float4 v = *(const float4*)(emb + (size_t)c * D_DIM + d0 + 4 * q);
                    int dd = 4 * q;
                    ec[(dd + 0) * CT + cl] = v.x;
                    ec[(dd + 1) * CT + cl] = v.y;
                    ec[(dd + 2) * CT + cl] = v.z;
                    ec[(dd + 3) * CT + cl] = v.w;
                }
            }
            __syncthreads();
#pragma unroll 4
            for (int d = 0; d < DC; ++d) {
                float4 zf = *(const float4*)&zc[d * PT + 4 * pg];
                float4 ef[4];
#pragma unroll
                for (int j = 0; j < 4; ++j)
                    ef[j] = *(const float4*)&ec[d * CT + 64 * j + 4 * cg];
                const float zz[4] = { zf.x, zf.y, zf.z, zf.w };
#pragma unroll
                for (int i = 0; i < 4; ++i) {
                    float zi = zz[i];
#pragma unroll
                    for (int j = 0; j < 4; ++j) {
                        acc[i][4 * j + 0] += zi * ef[j].x;
                        acc[i][4 * j + 1] += zi * ef[j].y;
                        acc[i][4 * j + 2] += zi * ef[j].z;
                        acc[i][4 * j + 3] += zi * ef[j].w;
                    }
                }
            }
        }
        {
#pragma clang fp contract(off) reassociate(off)
#pragma unroll
            for (int j = 0; j < 4; ++j) {
#pragma unroll
                for (int jj = 0; jj < 4; ++jj) {
                    int c = tile * CT + 64 * j + 4 * cg + jj;
                    float en = enorm[c];
#pragma unroll
                    for (int i = 0; i < 4; ++i) {
                        float t1 = zn[i] - 2.0f * acc[i][4 * j + jj];
                        float sc = t1 + en;
                        if (sc < best_v[i] || (sc == best_v[i] && c < best_i[i])) {
                            best_v[i] = sc; best_i[i] = c;
                        }
                    }
                }
            }
        }
    }
#pragma unroll
    for (int i = 0; i < 4; ++i) {
        int p = 4 * pg + i;
        redv[p * 17 + cg] = best_v[i];
        redi[p * 17 + cg] = best_i[i];
    }
    __syncthreads();
    if (t < PT) {
        float bv = FLT_MAX; int bi = 0;
        for (int g = 0; g < 16; ++g) {
            float v = redv[t * 17 + g];
            int  ix = redi[t * 17 + g];
            if (v < bv || (v == bv && ix < bi)) { bv = v; bi = ix; }
        }
        out[pb * PT + t] = bi;
    }
}

// ==========================================================================
extern "C" void kernel_launch(void* const* d_in, const int* in_sizes, int n_in,
                              void* d_out, int out_size, void* d_ws, size_t ws_size,
                              hipStream_t stream) {
    const float* z   = (const float*)d_in[0];
    const float* emb = (const float*)d_in[1];
    int* out = (int*)d_out;
    char* ws = (char*)d_ws;

    if (ws_size >= WS_NEED) {
        uint16_t* A2    = (uint16_t*)(ws + A2_OFF);
        uint16_t* B2    = (uint16_t*)(ws + B2_OFF);
        float*    en    = (float*)(ws + EN_OFF);
        float*    zn    = (float*)(ws + ZN_OFF);
        unsigned* cnt   = (unsigned*)(ws + CNT_OFF);
        unsigned* cand  = (unsigned*)(ws + CAND_OFF);

        hipMemsetAsync(cnt, 0, CNT_BYTES, stream);
        conv_e_kernel<<<K_CODES, 256, 0, stream>>>(emb, B2);
        conv_z_kernel<<<NPTS / 64, 256, 0, stream>>>(z, A2);
        enorm_kernel<<<K_CODES / 256, 256, 0, stream>>>(emb, en);
        znorm_kernel<<<NPTS / 256, 256, 0, stream>>>(z, zn);
        vq_mfma_kernel<<<NPTS / 64, 256, 0, stream>>>(A2, B2, en, cnt, cand);
        rescore_kernel<<<NPTS / 256, 256, 0, stream>>>(z, emb, en, zn, cnt, cand, out);
    } else {
        float* en = (float*)(ws + FB_EN_OFF);
        float* zn = (float*)(ws + FB_ZN_OFF);
        enorm_kernel<<<K_CODES / 256, 256, 0, stream>>>(emb, en);
        znorm_kernel<<<NPTS / 256, 256, 0, stream>>>(z, zn);
        vq_kernel<<<NPTS / PT, 256, 0, stream>>>(z, emb, en, zn, out);
    }
}